// Round 1
// baseline (940.560 us; speedup 1.0000x reference)
//
#include <hip/hip_runtime.h>
#include <hip/hip_bf16.h>

#define ND 128   // node feature dim (= H*C)
#define NH 8
#define NC 16
#define NED 4

static inline size_t alignup(size_t x){ return (x + 255) & ~size_t(255); }

// ---------------- CSR build ----------------

__global__ void hist_kernel(const int* __restrict__ dsts, const float4* __restrict__ ea4,
                            int* __restrict__ deg, float* __restrict__ easum, int E)
{
    int e = blockIdx.x * blockDim.x + threadIdx.x;
    if (e >= E) return;
    int d = dsts[e];
    atomicAdd(&deg[d], 1);
    float4 a = ea4[e];
    atomicAdd(&easum[d*4+0], a.x);
    atomicAdd(&easum[d*4+1], a.y);
    atomicAdd(&easum[d*4+2], a.z);
    atomicAdd(&easum[d*4+3], a.w);
}

__global__ __launch_bounds__(1024) void scan_kernel(const int* __restrict__ deg,
                                                    int* __restrict__ rowstart, int n)
{
    __shared__ int wsum[16];
    int tid = threadIdx.x;
    int lane = tid & 63, wid = tid >> 6;
    int carry = 0;
    for (int base = 0; base < n; base += 1024) {
        int idx = base + tid;
        int v = (idx < n) ? deg[idx] : 0;
        int s = v;
        #pragma unroll
        for (int o = 1; o < 64; o <<= 1) {
            int t = __shfl_up(s, o);
            if (lane >= o) s += t;
        }
        if (lane == 63) wsum[wid] = s;
        __syncthreads();
        int off = 0;
        #pragma unroll
        for (int w = 0; w < 16; ++w) {
            int ws_ = wsum[w];
            if (w < wid) off += ws_;
        }
        int total = 0;
        #pragma unroll
        for (int w = 0; w < 16; ++w) total += wsum[w];
        if (idx < n) rowstart[idx] = carry + off + (s - v);
        carry += total;
        __syncthreads();
    }
    if (tid == 0) rowstart[n] = carry;
}

__global__ void scatter_kernel(const int* __restrict__ srcs, const int* __restrict__ dsts,
                               const int* __restrict__ rowstart, int* __restrict__ cursor,
                               int2* __restrict__ sorted, int E)
{
    int e = blockIdx.x * blockDim.x + threadIdx.x;
    if (e >= E) return;
    int d = dsts[e];
    int pos = rowstart[d] + atomicAdd(&cursor[d], 1);
    sorted[pos] = make_int2(srcs[e], e);
}

// ---------------- GEMM: Y[n,128] = X[n,128] @ W[128,128] + b ----------------

__global__ __launch_bounds__(256) void gemm_xw(const float* __restrict__ X,
                                               const float* __restrict__ W,
                                               const float* __restrict__ bias,
                                               float* __restrict__ Y, int nrows)
{
    __shared__ float xs[64][128];
    int tid = threadIdx.x;
    int row0 = blockIdx.x * 64;

    const float4* X4 = (const float4*)X;
    float4* xs4 = (float4*)xs;
    #pragma unroll
    for (int i = tid; i < 64*32; i += 256) {
        int r = i >> 5;
        float4 v = make_float4(0.f, 0.f, 0.f, 0.f);
        if (row0 + r < nrows) v = X4[(size_t)(row0 + r) * 32 + (i & 31)];
        xs4[i] = v;
    }
    __syncthreads();

    int cg = tid & 31;          // column group: cols cg*4 .. cg*4+3
    int rg = (tid >> 5) * 8;    // row group: 8 rows
    float acc[8][4];
    float4 bv = ((const float4*)bias)[cg];
    #pragma unroll
    for (int r = 0; r < 8; r++) {
        acc[r][0] = bv.x; acc[r][1] = bv.y; acc[r][2] = bv.z; acc[r][3] = bv.w;
    }

    #pragma unroll 2
    for (int k = 0; k < 128; k++) {
        float4 wv = ((const float4*)(W + (size_t)k * 128))[cg];
        #pragma unroll
        for (int r = 0; r < 8; r++) {
            float xv = xs[rg + r][k];
            acc[r][0] = fmaf(xv, wv.x, acc[r][0]);
            acc[r][1] = fmaf(xv, wv.y, acc[r][1]);
            acc[r][2] = fmaf(xv, wv.z, acc[r][2]);
            acc[r][3] = fmaf(xv, wv.w, acc[r][3]);
        }
    }

    #pragma unroll
    for (int r = 0; r < 8; r++) {
        int row = row0 + rg + r;
        if (row < nrows) {
            float4 o = make_float4(acc[r][0], acc[r][1], acc[r][2], acc[r][3]);
            ((float4*)Y)[(size_t)row * 32 + cg] = o;
        }
    }
}

// ---------------- GATv2 edge accumulation (shared by both attn kernels) ----------------

__device__ __forceinline__ void gat_accumulate(
    int dstv, int c,
    const float* __restrict__ xl, const float* __restrict__ xr,
    const float* __restrict__ easum, const int* __restrict__ deg,
    const int* __restrict__ rowstart, const int2* __restrict__ sorted,
    const float4* __restrict__ ea4,
    const float* __restrict__ We, const float* __restrict__ att,
    float& acc_out, float& l_out)
{
    float xr_c = xr[(size_t)dstv * ND + c];
    float we0 = We[c], we1 = We[ND + c], we2 = We[2*ND + c], we3 = We[3*ND + c];
    float att_c = att[c];   // att[h][cc] with h = c>>4, cc = c&15  ->  flat index == c

    int dv = deg[dstv];
    float inv = 1.0f / (float)(dv > 0 ? dv : 1);

    // self loop (src = dst, ea = mean of incoming ea)
    float xl_self = xl[(size_t)dstv * ND + c];
    float e_c = easum[dstv*4+0]*inv*we0 + easum[dstv*4+1]*inv*we1
              + easum[dstv*4+2]*inv*we2 + easum[dstv*4+3]*inv*we3;
    float m = xl_self + xr_c + e_c;
    m = m > 0.f ? m : 0.2f * m;
    float al = m * att_c;
    al += __shfl_xor(al, 1); al += __shfl_xor(al, 2);
    al += __shfl_xor(al, 4); al += __shfl_xor(al, 8);

    float m_run = al, l_run = 1.0f, acc = xl_self;

    int p0 = rowstart[dstv];
    int p1 = p0 + dv;
    for (int p = p0; p < p1; ++p) {
        int2 se = sorted[p];
        float xls = xl[(size_t)se.x * ND + c];
        float4 av = ea4[se.y];
        float e2 = av.x*we0 + av.y*we1 + av.z*we2 + av.w*we3;
        float mm = xls + xr_c + e2;
        mm = mm > 0.f ? mm : 0.2f * mm;
        float a2 = mm * att_c;
        a2 += __shfl_xor(a2, 1); a2 += __shfl_xor(a2, 2);
        a2 += __shfl_xor(a2, 4); a2 += __shfl_xor(a2, 8);

        float mnew = fmaxf(m_run, a2);
        float sc = __expf(m_run - mnew);
        float pe = __expf(a2 - mnew);
        l_run = l_run * sc + pe;
        acc = acc * sc + pe * xls;
        m_run = mnew;
    }
    acc_out = acc;
    l_out = l_run;
}

// layers 0,1: concat heads (out dim 128), +bias, ELU, LN(128), residual
__global__ __launch_bounds__(128) void attn_concat(
    const float* __restrict__ xl, const float* __restrict__ xr,
    const float* __restrict__ xin,
    const float* __restrict__ easum, const int* __restrict__ deg,
    const int* __restrict__ rowstart, const int2* __restrict__ sorted,
    const float4* __restrict__ ea4,
    const float* __restrict__ We, const float* __restrict__ att,
    const float* __restrict__ bias, const float* __restrict__ g, const float* __restrict__ be,
    float* __restrict__ out, int n)
{
    int dstv = blockIdx.x;
    if (dstv >= n) return;
    int c = threadIdx.x;
    int lane = c & 63, wid = c >> 6;

    float acc, l_run;
    gat_accumulate(dstv, c, xl, xr, easum, deg, rowstart, sorted, ea4, We, att, acc, l_run);

    float hv = acc / l_run + bias[c];
    hv = hv > 0.f ? hv : (__expf(hv) - 1.0f);   // ELU

    // LayerNorm over 128 (2 waves)
    float s1 = hv, s2 = hv * hv;
    #pragma unroll
    for (int o = 1; o < 64; o <<= 1) { s1 += __shfl_xor(s1, o); s2 += __shfl_xor(s2, o); }
    __shared__ float red[4];
    if (lane == 0) { red[wid*2] = s1; red[wid*2+1] = s2; }
    __syncthreads();
    float ts = red[0] + red[2], tq = red[1] + red[3];
    float mu = ts * (1.0f / ND);
    float var = tq * (1.0f / ND) - mu * mu;
    float rstd = rsqrtf(var + 1e-5f);
    float r = (hv - mu) * rstd * g[c] + be[c] + xin[(size_t)dstv * ND + c];
    out[(size_t)dstv * ND + c] = r;
}

// layer 2: mean over heads (out dim 16), +bias, ELU, LN(16), then @Wout[16,128]+bout
__global__ __launch_bounds__(128) void attn_final(
    const float* __restrict__ xl, const float* __restrict__ xr,
    const float* __restrict__ easum, const int* __restrict__ deg,
    const int* __restrict__ rowstart, const int2* __restrict__ sorted,
    const float4* __restrict__ ea4,
    const float* __restrict__ We, const float* __restrict__ att,
    const float* __restrict__ b2, const float* __restrict__ g2, const float* __restrict__ be2,
    const float* __restrict__ Wout, const float* __restrict__ bout,
    float* __restrict__ out, int n)
{
    int dstv = blockIdx.x;
    if (dstv >= n) return;
    int c = threadIdx.x;

    float acc, l_run;
    gat_accumulate(dstv, c, xl, xr, easum, deg, rowstart, sorted, ea4, We, att, acc, l_run);

    __shared__ float accs[ND];
    __shared__ float h16[NC];
    accs[c] = acc / l_run;
    __syncthreads();
    if (c < NC) {
        float s = 0.f;
        #pragma unroll
        for (int hh = 0; hh < NH; hh++) s += accs[hh * NC + c];
        s = s * (1.0f / NH) + b2[c];
        s = s > 0.f ? s : (__expf(s) - 1.0f);   // ELU
        h16[c] = s;
    }
    __syncthreads();

    float mu = 0.f, sq = 0.f;
    #pragma unroll
    for (int k = 0; k < NC; k++) { float v = h16[k]; mu += v; sq += v * v; }
    mu *= (1.0f / NC);
    float var = sq * (1.0f / NC) - mu * mu;
    float rstd = rsqrtf(var + 1e-5f);

    float o = bout[c];
    #pragma unroll
    for (int k = 0; k < NC; k++) {
        float t = (h16[k] - mu) * rstd * g2[k] + be2[k];
        o = fmaf(t, Wout[(size_t)k * ND + c], o);
    }
    out[(size_t)dstv * ND + c] = o;
}

// ---------------- launch ----------------

extern "C" void kernel_launch(void* const* d_in, const int* in_sizes, int n_in,
                              void* d_out, int out_size, void* d_ws, size_t ws_size,
                              hipStream_t stream)
{
    const float* x_in = (const float*)d_in[0];
    const int*   ei   = (const int*)d_in[1];
    const float* ea   = (const float*)d_in[2];
    const int N = in_sizes[0] / ND;
    const int E = in_sizes[1] / 2;
    const int* srcs = ei;
    const int* dsts = ei + E;
    const float4* ea4 = (const float4*)ea;

    // per-layer params: d_in[3+9*l ...]
    const float *Wl[3], *bl[3], *Wr[3], *br[3], *We[3], *att[3], *bb[3], *gg[3], *be[3];
    for (int l = 0; l < 3; l++) {
        int b = 3 + 9 * l;
        Wl[l]  = (const float*)d_in[b + 0];
        bl[l]  = (const float*)d_in[b + 1];
        Wr[l]  = (const float*)d_in[b + 2];
        br[l]  = (const float*)d_in[b + 3];
        We[l]  = (const float*)d_in[b + 4];
        att[l] = (const float*)d_in[b + 5];
        bb[l]  = (const float*)d_in[b + 6];
        gg[l]  = (const float*)d_in[b + 7];
        be[l]  = (const float*)d_in[b + 8];
    }
    const float* Wout = (const float*)d_in[30];
    const float* bout = (const float*)d_in[31];

    char* ws = (char*)d_ws;
    size_t off = 0;
    int* deg      = (int*)(ws + off);   off = alignup(off + (size_t)N * 4);
    int* cursor   = (int*)(ws + off);   off = alignup(off + (size_t)N * 4);
    float* easum  = (float*)(ws + off); off = alignup(off + (size_t)N * 16);
    size_t zero_bytes = off;
    int* rowstart = (int*)(ws + off);   off = alignup(off + (size_t)(N + 1) * 4);
    int2* sorted  = (int2*)(ws + off);  off = alignup(off + (size_t)E * 8);
    float* xl     = (float*)(ws + off); off = alignup(off + (size_t)N * ND * 4);
    float* xr     = (float*)(ws + off); off = alignup(off + (size_t)N * ND * 4);
    float* xa     = (float*)(ws + off); off = alignup(off + (size_t)N * ND * 4);
    float* xb     = (float*)d_out;      // reuse output buffer as layer-1 output

    hipMemsetAsync(d_ws, 0, zero_bytes, stream);

    int ethreads = 256;
    int eblocks = (E + ethreads - 1) / ethreads;
    hist_kernel<<<eblocks, ethreads, 0, stream>>>(dsts, ea4, deg, easum, E);
    scan_kernel<<<1, 1024, 0, stream>>>(deg, rowstart, N);
    scatter_kernel<<<eblocks, ethreads, 0, stream>>>(srcs, dsts, rowstart, cursor, sorted, E);

    int gblocks = (N + 63) / 64;

    // ---- layer 0 (input x_in, residual x_in, out -> xa) ----
    gemm_xw<<<gblocks, 256, 0, stream>>>(x_in, Wl[0], bl[0], xl, N);
    gemm_xw<<<gblocks, 256, 0, stream>>>(x_in, Wr[0], br[0], xr, N);
    attn_concat<<<N, 128, 0, stream>>>(xl, xr, x_in, easum, deg, rowstart, sorted, ea4,
                                       We[0], att[0], bb[0], gg[0], be[0], xa, N);

    // ---- layer 1 (input xa, residual xa, out -> xb=d_out) ----
    gemm_xw<<<gblocks, 256, 0, stream>>>(xa, Wl[1], bl[1], xl, N);
    gemm_xw<<<gblocks, 256, 0, stream>>>(xa, Wr[1], br[1], xr, N);
    attn_concat<<<N, 128, 0, stream>>>(xl, xr, xa, easum, deg, rowstart, sorted, ea4,
                                       We[1], att[1], bb[1], gg[1], be[1], xb, N);

    // ---- layer 2 (input xb) + output projection -> d_out ----
    gemm_xw<<<gblocks, 256, 0, stream>>>(xb, Wl[2], bl[2], xl, N);
    gemm_xw<<<gblocks, 256, 0, stream>>>(xb, Wr[2], br[2], xr, N);
    attn_final<<<N, 128, 0, stream>>>(xl, xr, easum, deg, rowstart, sorted, ea4,
                                      We[2], att[2], bb[2], gg[2], be[2],
                                      Wout, bout, (float*)d_out, N);
}

// Round 2
// 658.212 us; speedup vs baseline: 1.4290x; 1.4290x over previous
//
#include <hip/hip_runtime.h>
#include <hip/hip_bf16.h>

#define ND 128   // node feature dim (= H*C)
#define NH 8
#define NC 16

static inline size_t alignup(size_t x){ return (x + 255) & ~size_t(255); }

__device__ __forceinline__ ushort f2bf(float f){
    __hip_bfloat16 h = __float2bfloat16(f);
    return *reinterpret_cast<ushort*>(&h);
}

// ---------------- CSR build ----------------

__global__ void hist_kernel(const int* __restrict__ dsts, int* __restrict__ deg, int E)
{
    int e = blockIdx.x * blockDim.x + threadIdx.x;
    if (e >= E) return;
    atomicAdd(&deg[dsts[e]], 1);
}

__global__ __launch_bounds__(1024) void scan_kernel(const int* __restrict__ deg,
                                                    int* __restrict__ rowstart, int n)
{
    __shared__ int wsum[16];
    int tid = threadIdx.x;
    int lane = tid & 63, wid = tid >> 6;
    int carry = 0;
    for (int base = 0; base < n; base += 1024) {
        int idx = base + tid;
        int v = (idx < n) ? deg[idx] : 0;
        int s = v;
        #pragma unroll
        for (int o = 1; o < 64; o <<= 1) {
            int t = __shfl_up(s, o);
            if (lane >= o) s += t;
        }
        if (lane == 63) wsum[wid] = s;
        __syncthreads();
        int off = 0;
        #pragma unroll
        for (int w = 0; w < 16; ++w) {
            int ws_ = wsum[w];
            if (w < wid) off += ws_;
        }
        int total = 0;
        #pragma unroll
        for (int w = 0; w < 16; ++w) total += wsum[w];
        if (idx < n) rowstart[idx] = carry + off + (s - v);
        carry += total;
        __syncthreads();
    }
    if (tid == 0) rowstart[n] = carry;
}

__global__ void scatter_kernel(const int* __restrict__ srcs, const int* __restrict__ dsts,
                               const float4* __restrict__ ea4,
                               const int* __restrict__ rowstart, int* __restrict__ cursor,
                               int* __restrict__ src_sorted, float4* __restrict__ ea_sorted, int E)
{
    int e = blockIdx.x * blockDim.x + threadIdx.x;
    if (e >= E) return;
    int d = dsts[e];
    int pos = rowstart[d] + atomicAdd(&cursor[d], 1);
    src_sorted[pos] = srcs[e];
    ea_sorted[pos] = ea4[e];
}

// ---------------- fused GEMM: XL(bf16) = X@Wl+bl, XR(f32) = X@Wr+br ----------------

__global__ __launch_bounds__(256) void gemm_xw2(const float* __restrict__ X,
                                                const float* __restrict__ Wl,
                                                const float* __restrict__ bl,
                                                const float* __restrict__ Wr,
                                                const float* __restrict__ br,
                                                ushort* __restrict__ XLB,
                                                float* __restrict__ XR, int nrows)
{
    __shared__ float xs[64][128];
    int tid = threadIdx.x;
    int row0 = blockIdx.x * 64;

    const float4* X4 = (const float4*)X;
    float4* xs4 = (float4*)xs;
    #pragma unroll
    for (int i = tid; i < 64*32; i += 256) {
        int r = i >> 5;
        float4 v = make_float4(0.f, 0.f, 0.f, 0.f);
        if (row0 + r < nrows) v = X4[(size_t)(row0 + r) * 32 + (i & 31)];
        xs4[i] = v;
    }
    __syncthreads();

    int cg = tid & 31;          // cols cg*4 .. cg*4+3
    int rg = (tid >> 5) * 8;    // 8 rows
    float accl[8][4], accr[8][4];
    float4 blv = ((const float4*)bl)[cg];
    float4 brv = ((const float4*)br)[cg];
    #pragma unroll
    for (int r = 0; r < 8; r++) {
        accl[r][0] = blv.x; accl[r][1] = blv.y; accl[r][2] = blv.z; accl[r][3] = blv.w;
        accr[r][0] = brv.x; accr[r][1] = brv.y; accr[r][2] = brv.z; accr[r][3] = brv.w;
    }

    #pragma unroll 2
    for (int k = 0; k < 128; k++) {
        float4 wl = ((const float4*)(Wl + (size_t)k * 128))[cg];
        float4 wr = ((const float4*)(Wr + (size_t)k * 128))[cg];
        #pragma unroll
        for (int r = 0; r < 8; r++) {
            float xv = xs[rg + r][k];
            accl[r][0] = fmaf(xv, wl.x, accl[r][0]);
            accl[r][1] = fmaf(xv, wl.y, accl[r][1]);
            accl[r][2] = fmaf(xv, wl.z, accl[r][2]);
            accl[r][3] = fmaf(xv, wl.w, accl[r][3]);
            accr[r][0] = fmaf(xv, wr.x, accr[r][0]);
            accr[r][1] = fmaf(xv, wr.y, accr[r][1]);
            accr[r][2] = fmaf(xv, wr.z, accr[r][2]);
            accr[r][3] = fmaf(xv, wr.w, accr[r][3]);
        }
    }

    #pragma unroll
    for (int r = 0; r < 8; r++) {
        int row = row0 + rg + r;
        if (row < nrows) {
            ushort4 ob;
            ob.x = f2bf(accl[r][0]); ob.y = f2bf(accl[r][1]);
            ob.z = f2bf(accl[r][2]); ob.w = f2bf(accl[r][3]);
            ((ushort4*)XLB)[(size_t)row * 32 + cg] = ob;
            float4 of = make_float4(accr[r][0], accr[r][1], accr[r][2], accr[r][3]);
            ((float4*)XR)[(size_t)row * 32 + cg] = of;
        }
    }
}

// ---------------- GATv2 edge accumulation: 1 wave per dst, 2 channels/thread ------------
// lane t handles channels c0=2t, c1=2t+1; head = t>>3; head-local reduce = xor 1,2,4

__device__ __forceinline__ void gat_wave(
    int dstv, int t,
    const uint* __restrict__ xl_u, const float* __restrict__ xr,
    const int* __restrict__ rowstart,
    const int* __restrict__ src_sorted, const float4* __restrict__ ea_sorted,
    const float* __restrict__ We, const float* __restrict__ att,
    float& r0_out, float& r1_out, float& l_out)
{
    float2 xrv = ((const float2*)(xr + (size_t)dstv * ND))[t];
    float2 we0 = ((const float2*)(We))[t];
    float2 we1 = ((const float2*)(We + ND))[t];
    float2 we2 = ((const float2*)(We + 2*ND))[t];
    float2 we3 = ((const float2*)(We + 3*ND))[t];
    float2 attv = ((const float2*)att)[t];

    int p0 = rowstart[dstv];
    int p1 = rowstart[dstv + 1];
    int dv = p1 - p0;

    uint xsw = xl_u[(size_t)dstv * 64 + t];   // self-loop xl, loaded early

    float s0 = 0.f, s1 = 0.f, s2 = 0.f, s3 = 0.f;     // edge-attr sums
    float m_run = -3.0e38f, l_run = 0.f, a0 = 0.f, a1 = 0.f;

    int sA = 0; uint xA = 0; float4 eA = make_float4(0,0,0,0);
    if (dv > 0) {
        sA = src_sorted[p0];
        xA = xl_u[(size_t)sA * 64 + t];
        eA = ea_sorted[p0];
    }
    for (int p = p0; p < p1; ++p) {
        int sB = 0; uint xB = 0; float4 eB = make_float4(0,0,0,0);
        if (p + 1 < p1) {
            sB = src_sorted[p + 1];
            xB = xl_u[(size_t)sB * 64 + t];
            eB = ea_sorted[p + 1];
        }
        float x0 = __uint_as_float(xA << 16);
        float x1 = __uint_as_float(xA & 0xffff0000u);
        s0 += eA.x; s1 += eA.y; s2 += eA.z; s3 += eA.w;
        float e0 = eA.x*we0.x + eA.y*we1.x + eA.z*we2.x + eA.w*we3.x;
        float e1 = eA.x*we0.y + eA.y*we1.y + eA.z*we2.y + eA.w*we3.y;
        float m0 = x0 + xrv.x + e0; m0 = m0 > 0.f ? m0 : 0.2f * m0;
        float m1 = x1 + xrv.y + e1; m1 = m1 > 0.f ? m1 : 0.2f * m1;
        float al = m0 * attv.x + m1 * attv.y;
        al += __shfl_xor(al, 1); al += __shfl_xor(al, 2); al += __shfl_xor(al, 4);
        float mnew = fmaxf(m_run, al);
        float sc = __expf(m_run - mnew);
        float pe = __expf(al - mnew);
        l_run = l_run * sc + pe;
        a0 = a0 * sc + pe * x0;
        a1 = a1 * sc + pe * x1;
        m_run = mnew;
        xA = xB; eA = eB; sA = sB;
    }

    // self loop last: ea = mean of incoming, src = dst
    float inv = 1.0f / (float)(dv > 0 ? dv : 1);
    float x0 = __uint_as_float(xsw << 16);
    float x1 = __uint_as_float(xsw & 0xffff0000u);
    float e0 = (s0*we0.x + s1*we1.x + s2*we2.x + s3*we3.x) * inv;
    float e1 = (s0*we0.y + s1*we1.y + s2*we2.y + s3*we3.y) * inv;
    float m0 = x0 + xrv.x + e0; m0 = m0 > 0.f ? m0 : 0.2f * m0;
    float m1 = x1 + xrv.y + e1; m1 = m1 > 0.f ? m1 : 0.2f * m1;
    float al = m0 * attv.x + m1 * attv.y;
    al += __shfl_xor(al, 1); al += __shfl_xor(al, 2); al += __shfl_xor(al, 4);
    float mnew = fmaxf(m_run, al);
    float sc = __expf(m_run - mnew);
    float pe = __expf(al - mnew);
    l_out = l_run * sc + pe;
    r0_out = a0 * sc + pe * x0;
    r1_out = a1 * sc + pe * x1;
}

// layers 0,1: concat heads, +bias, ELU, LN(128), residual. 4 dst per 256-thread block.
__global__ __launch_bounds__(256) void attn_concat(
    const ushort* __restrict__ xlb, const float* __restrict__ xr,
    const float* __restrict__ xin,
    const int* __restrict__ rowstart,
    const int* __restrict__ src_sorted, const float4* __restrict__ ea_sorted,
    const float* __restrict__ We, const float* __restrict__ att,
    const float* __restrict__ bias, const float* __restrict__ g, const float* __restrict__ be,
    float* __restrict__ out, int n)
{
    int wid = threadIdx.x >> 6;
    int t = threadIdx.x & 63;
    int dstv = blockIdx.x * 4 + wid;
    if (dstv >= n) return;

    float r0, r1, l;
    gat_wave(dstv, t, (const uint*)xlb, xr, rowstart, src_sorted, ea_sorted, We, att, r0, r1, l);

    float2 bv = ((const float2*)bias)[t];
    float linv = 1.0f / l;
    float h0 = r0 * linv + bv.x;
    float h1 = r1 * linv + bv.y;
    h0 = h0 > 0.f ? h0 : (__expf(h0) - 1.0f);
    h1 = h1 > 0.f ? h1 : (__expf(h1) - 1.0f);

    float ss = h0 + h1, qq = h0*h0 + h1*h1;
    #pragma unroll
    for (int o = 1; o < 64; o <<= 1) { ss += __shfl_xor(ss, o); qq += __shfl_xor(qq, o); }
    float mu = ss * (1.0f / ND);
    float var = qq * (1.0f / ND) - mu * mu;
    float rstd = rsqrtf(var + 1e-5f);

    float2 gv = ((const float2*)g)[t];
    float2 bev = ((const float2*)be)[t];
    float2 xiv = ((const float2*)(xin + (size_t)dstv * ND))[t];
    float2 o2;
    o2.x = (h0 - mu) * rstd * gv.x + bev.x + xiv.x;
    o2.y = (h1 - mu) * rstd * gv.y + bev.y + xiv.y;
    ((float2*)(out + (size_t)dstv * ND))[t] = o2;
}

// layer 2: mean over heads, +bias, ELU, LN(16), @Wout[16,128]+bout
__global__ __launch_bounds__(256) void attn_final(
    const ushort* __restrict__ xlb, const float* __restrict__ xr,
    const int* __restrict__ rowstart,
    const int* __restrict__ src_sorted, const float4* __restrict__ ea_sorted,
    const float* __restrict__ We, const float* __restrict__ att,
    const float* __restrict__ b2, const float* __restrict__ g2, const float* __restrict__ be2,
    const float* __restrict__ Wout, const float* __restrict__ bout,
    float* __restrict__ out, int n)
{
    __shared__ float h16s[4][16];
    int wid = threadIdx.x >> 6;
    int t = threadIdx.x & 63;
    int dstv = blockIdx.x * 4 + wid;
    if (dstv >= n) return;

    float r0, r1, l;
    gat_wave(dstv, t, (const uint*)xlb, xr, rowstart, src_sorted, ea_sorted, We, att, r0, r1, l);
    float linv = 1.0f / l;
    r0 *= linv; r1 *= linv;

    // mean over 8 heads: sum over lanes differing in bits 3,4,5
    float v0 = r0, v1 = r1;
    #pragma unroll
    for (int o = 8; o < 64; o <<= 1) { v0 += __shfl_xor(v0, o); v1 += __shfl_xor(v1, o); }
    int cc = t & 7;   // channel pair index: channels 2cc, 2cc+1
    float2 b2v = ((const float2*)b2)[cc];
    v0 = v0 * (1.0f / NH) + b2v.x;
    v1 = v1 * (1.0f / NH) + b2v.y;
    v0 = v0 > 0.f ? v0 : (__expf(v0) - 1.0f);
    v1 = v1 > 0.f ? v1 : (__expf(v1) - 1.0f);

    // LN over 16 (values duplicated across the 8 head-groups)
    float ss = v0 + v1, qq = v0*v0 + v1*v1;
    #pragma unroll
    for (int o = 1; o < 8; o <<= 1) { ss += __shfl_xor(ss, o); qq += __shfl_xor(qq, o); }
    float mu = ss * (1.0f / NC);
    float var = qq * (1.0f / NC) - mu * mu;
    float rstd = rsqrtf(var + 1e-5f);
    float2 g2v = ((const float2*)g2)[cc];
    float2 be2v = ((const float2*)be2)[cc];
    float t0 = (v0 - mu) * rstd * g2v.x + be2v.x;
    float t1 = (v1 - mu) * rstd * g2v.y + be2v.y;

    if (t < 8) { h16s[wid][2*t] = t0; h16s[wid][2*t + 1] = t1; }

    float2 ov = ((const float2*)bout)[t];
    #pragma unroll
    for (int k = 0; k < NC; k++) {
        float hk = h16s[wid][k];
        float2 wv = ((const float2*)Wout)[k * 64 + t];
        ov.x = fmaf(hk, wv.x, ov.x);
        ov.y = fmaf(hk, wv.y, ov.y);
    }
    ((float2*)(out + (size_t)dstv * ND))[t] = ov;
}

// ---------------- launch ----------------

extern "C" void kernel_launch(void* const* d_in, const int* in_sizes, int n_in,
                              void* d_out, int out_size, void* d_ws, size_t ws_size,
                              hipStream_t stream)
{
    const float* x_in = (const float*)d_in[0];
    const int*   ei   = (const int*)d_in[1];
    const float* ea   = (const float*)d_in[2];
    const int N = in_sizes[0] / ND;
    const int E = in_sizes[1] / 2;
    const int* srcs = ei;
    const int* dsts = ei + E;
    const float4* ea4 = (const float4*)ea;

    const float *Wl[3], *bl[3], *Wr[3], *br[3], *We[3], *att[3], *bb[3], *gg[3], *be[3];
    for (int l = 0; l < 3; l++) {
        int b = 3 + 9 * l;
        Wl[l]  = (const float*)d_in[b + 0];
        bl[l]  = (const float*)d_in[b + 1];
        Wr[l]  = (const float*)d_in[b + 2];
        br[l]  = (const float*)d_in[b + 3];
        We[l]  = (const float*)d_in[b + 4];
        att[l] = (const float*)d_in[b + 5];
        bb[l]  = (const float*)d_in[b + 6];
        gg[l]  = (const float*)d_in[b + 7];
        be[l]  = (const float*)d_in[b + 8];
    }
    const float* Wout = (const float*)d_in[30];
    const float* bout = (const float*)d_in[31];

    char* ws = (char*)d_ws;
    size_t off = 0;
    int* deg        = (int*)(ws + off);    off = alignup(off + (size_t)N * 4);
    int* cursor     = (int*)(ws + off);    off = alignup(off + (size_t)N * 4);
    size_t zero_bytes = off;
    int* rowstart   = (int*)(ws + off);    off = alignup(off + (size_t)(N + 1) * 4);
    int* src_sorted = (int*)(ws + off);    off = alignup(off + (size_t)E * 4);
    float4* ea_sorted = (float4*)(ws + off); off = alignup(off + (size_t)E * 16);
    ushort* xlb     = (ushort*)(ws + off); off = alignup(off + (size_t)N * ND * 2);
    float* xr       = (float*)(ws + off);  off = alignup(off + (size_t)N * ND * 4);
    float* xa       = (float*)(ws + off);  off = alignup(off + (size_t)N * ND * 4);
    float* xb       = (float*)d_out;       // layer-1 output lives in d_out

    hipMemsetAsync(d_ws, 0, zero_bytes, stream);

    int ethreads = 256;
    int eblocks = (E + ethreads - 1) / ethreads;
    hist_kernel<<<eblocks, ethreads, 0, stream>>>(dsts, deg, E);
    scan_kernel<<<1, 1024, 0, stream>>>(deg, rowstart, N);
    scatter_kernel<<<eblocks, ethreads, 0, stream>>>(srcs, dsts, ea4, rowstart, cursor,
                                                     src_sorted, ea_sorted, E);

    int gblocks = (N + 63) / 64;
    int ablocks = (N + 3) / 4;

    // layer 0
    gemm_xw2<<<gblocks, 256, 0, stream>>>(x_in, Wl[0], bl[0], Wr[0], br[0], xlb, xr, N);
    attn_concat<<<ablocks, 256, 0, stream>>>(xlb, xr, x_in, rowstart, src_sorted, ea_sorted,
                                             We[0], att[0], bb[0], gg[0], be[0], xa, N);
    // layer 1
    gemm_xw2<<<gblocks, 256, 0, stream>>>(xa, Wl[1], bl[1], Wr[1], br[1], xlb, xr, N);
    attn_concat<<<ablocks, 256, 0, stream>>>(xlb, xr, xa, rowstart, src_sorted, ea_sorted,
                                             We[1], att[1], bb[1], gg[1], be[1], xb, N);
    // layer 2 + output projection
    gemm_xw2<<<gblocks, 256, 0, stream>>>(xb, Wl[2], bl[2], Wr[2], br[2], xlb, xr, N);
    attn_final<<<ablocks, 256, 0, stream>>>(xlb, xr, rowstart, src_sorted, ea_sorted,
                                            We[2], att[2], bb[2], gg[2], be[2],
                                            Wout, bout, (float*)d_out, N);
}

// Round 3
// 527.661 us; speedup vs baseline: 1.7825x; 1.2474x over previous
//
#include <hip/hip_runtime.h>
#include <hip/hip_bf16.h>

#define ND 128   // node feature dim (= H*C)
#define NH 8
#define NC 16

static inline size_t alignup(size_t x){ return (x + 255) & ~size_t(255); }

__device__ __forceinline__ ushort f2bf(float f){
    __hip_bfloat16 h = __float2bfloat16(f);
    return *reinterpret_cast<ushort*>(&h);
}

// sum over each aligned 8-lane group (head group), pure-VALU DPP butterfly:
// stages xor1 (quad_perm[1,0,3,2]=0xB1), xor2 (quad_perm[2,3,0,1]=0x4E),
// cross-half (row_half_mirror=0x141). Union of the 3 involutions covers all 8 lanes.
__device__ __forceinline__ float hred8(float x){
    int y;
    y = __builtin_amdgcn_mov_dpp(__float_as_int(x), 0xB1, 0xF, 0xF, true);
    x += __int_as_float(y);
    y = __builtin_amdgcn_mov_dpp(__float_as_int(x), 0x4E, 0xF, 0xF, true);
    x += __int_as_float(y);
    y = __builtin_amdgcn_mov_dpp(__float_as_int(x), 0x141, 0xF, 0xF, true);
    x += __int_as_float(y);
    return x;
}

// ---------------- CSR build ----------------

__global__ void hist_kernel(const int* __restrict__ dsts, int* __restrict__ deg, int E)
{
    int e = blockIdx.x * blockDim.x + threadIdx.x;
    if (e >= E) return;
    atomicAdd(&deg[dsts[e]], 1);
}

// rowstart = exclusive cumsum of PADDED degrees (each row padded to multiple of 4)
__global__ __launch_bounds__(1024) void scan_kernel(const int* __restrict__ deg,
                                                    int* __restrict__ rowstart, int n)
{
    __shared__ int wsum[16];
    int tid = threadIdx.x;
    int lane = tid & 63, wid = tid >> 6;
    int carry = 0;
    for (int base = 0; base < n; base += 1024) {
        int idx = base + tid;
        int v = (idx < n) ? ((deg[idx] + 3) & ~3) : 0;
        int s = v;
        #pragma unroll
        for (int o = 1; o < 64; o <<= 1) {
            int t = __shfl_up(s, o);
            if (lane >= o) s += t;
        }
        if (lane == 63) wsum[wid] = s;
        __syncthreads();
        int off = 0;
        #pragma unroll
        for (int w = 0; w < 16; ++w) {
            int ws_ = wsum[w];
            if (w < wid) off += ws_;
        }
        int total = 0;
        #pragma unroll
        for (int w = 0; w < 16; ++w) total += wsum[w];
        if (idx < n) rowstart[idx] = carry + off + (s - v);
        carry += total;
        __syncthreads();
    }
    if (tid == 0) rowstart[n] = carry;
}

__global__ void scatter_kernel(const int* __restrict__ srcs, const int* __restrict__ dsts,
                               const float4* __restrict__ ea4,
                               const int* __restrict__ rowstart, int* __restrict__ cursor,
                               int* __restrict__ src_sorted, float4* __restrict__ ea_sorted, int E)
{
    int e = blockIdx.x * blockDim.x + threadIdx.x;
    if (e >= E) return;
    int d = dsts[e];
    int pos = rowstart[d] + atomicAdd(&cursor[d], 1);
    src_sorted[pos] = srcs[e];
    ea_sorted[pos] = ea4[e];
}

// ---------------- fused GEMM: XL(bf16) = X@Wl+bl, XR(f32) = X@Wr+br ----------------

__global__ __launch_bounds__(256) void gemm_xw2(const float* __restrict__ X,
                                                const float* __restrict__ Wl,
                                                const float* __restrict__ bl,
                                                const float* __restrict__ Wr,
                                                const float* __restrict__ br,
                                                ushort* __restrict__ XLB,
                                                float* __restrict__ XR, int nrows)
{
    __shared__ float xs[64][128];
    int tid = threadIdx.x;
    int row0 = blockIdx.x * 64;

    const float4* X4 = (const float4*)X;
    float4* xs4 = (float4*)xs;
    #pragma unroll
    for (int i = tid; i < 64*32; i += 256) {
        int r = i >> 5;
        float4 v = make_float4(0.f, 0.f, 0.f, 0.f);
        if (row0 + r < nrows) v = X4[(size_t)(row0 + r) * 32 + (i & 31)];
        xs4[i] = v;
    }
    __syncthreads();

    int cg = tid & 31;          // cols cg*4 .. cg*4+3
    int rg = (tid >> 5) * 8;    // 8 rows
    float accl[8][4], accr[8][4];
    float4 blv = ((const float4*)bl)[cg];
    float4 brv = ((const float4*)br)[cg];
    #pragma unroll
    for (int r = 0; r < 8; r++) {
        accl[r][0] = blv.x; accl[r][1] = blv.y; accl[r][2] = blv.z; accl[r][3] = blv.w;
        accr[r][0] = brv.x; accr[r][1] = brv.y; accr[r][2] = brv.z; accr[r][3] = brv.w;
    }

    #pragma unroll 2
    for (int k = 0; k < 128; k++) {
        float4 wl = ((const float4*)(Wl + (size_t)k * 128))[cg];
        float4 wr = ((const float4*)(Wr + (size_t)k * 128))[cg];
        #pragma unroll
        for (int r = 0; r < 8; r++) {
            float xv = xs[rg + r][k];
            accl[r][0] = fmaf(xv, wl.x, accl[r][0]);
            accl[r][1] = fmaf(xv, wl.y, accl[r][1]);
            accl[r][2] = fmaf(xv, wl.z, accl[r][2]);
            accl[r][3] = fmaf(xv, wl.w, accl[r][3]);
            accr[r][0] = fmaf(xv, wr.x, accr[r][0]);
            accr[r][1] = fmaf(xv, wr.y, accr[r][1]);
            accr[r][2] = fmaf(xv, wr.z, accr[r][2]);
            accr[r][3] = fmaf(xv, wr.w, accr[r][3]);
        }
    }

    #pragma unroll
    for (int r = 0; r < 8; r++) {
        int row = row0 + rg + r;
        if (row < nrows) {
            ushort4 ob;
            ob.x = f2bf(accl[r][0]); ob.y = f2bf(accl[r][1]);
            ob.z = f2bf(accl[r][2]); ob.w = f2bf(accl[r][3]);
            ((ushort4*)XLB)[(size_t)row * 32 + cg] = ob;
            float4 of = make_float4(accr[r][0], accr[r][1], accr[r][2], accr[r][3]);
            ((float4*)XR)[(size_t)row * 32 + cg] = of;
        }
    }
}

// ---------------- GATv2 edge accumulation: 1 wave/dst, 2 ch/lane, 4 edges/batch ---------

__device__ __forceinline__ void gat_wave(
    int dstv, int t,
    const uint* __restrict__ xl_u, const float* __restrict__ xr,
    const int* __restrict__ rowstart, const int* __restrict__ deg,
    const int* __restrict__ src_sorted, const float4* __restrict__ ea_sorted,
    const float* __restrict__ We, const float* __restrict__ att,
    float& r0_out, float& r1_out, float& l_out)
{
    float2 xrv = ((const float2*)(xr + (size_t)dstv * ND))[t];
    float2 we0 = ((const float2*)(We))[t];
    float2 we1 = ((const float2*)(We + ND))[t];
    float2 we2 = ((const float2*)(We + 2*ND))[t];
    float2 we3 = ((const float2*)(We + 3*ND))[t];
    float2 attv = ((const float2*)att)[t];

    int p0 = rowstart[dstv];
    int dv = deg[dstv];
    int p1 = p0 + dv;

    uint xsw = xl_u[((size_t)dstv << 6) + t];   // self-loop xl

    const uint* xlt = xl_u + t;

    float s0 = 0.f, s1 = 0.f, s2 = 0.f, s3 = 0.f;       // edge-attr sums (pads are 0)
    float m_run = -3.0e38f, l_run = 0.f, a0 = 0.f, a1 = 0.f;

    int4 s4 = {};
    if (p0 < p1) s4 = *(const int4*)(src_sorted + p0);

    for (int p = p0; p < p1; p += 4) {
        // gathers for current batch (addresses from prefetched s4)
        uint xg0 = xlt[(size_t)s4.x << 6];
        uint xg1 = xlt[(size_t)s4.y << 6];
        uint xg2 = xlt[(size_t)s4.z << 6];
        uint xg3 = xlt[(size_t)s4.w << 6];
        // edge attrs (pad slots are zero-filled)
        float4 ea0 = ea_sorted[p];
        float4 ea1 = ea_sorted[p + 1];
        float4 ea2 = ea_sorted[p + 2];
        float4 ea3 = ea_sorted[p + 3];
        // prefetch next batch's srcs (guard slots allocated past the end)
        s4 = *(const int4*)(src_sorted + p + 4);

        // e-dot + xr (per slot, per channel)
        float b00 = fmaf(ea0.x, we0.x, fmaf(ea0.y, we1.x, fmaf(ea0.z, we2.x, fmaf(ea0.w, we3.x, xrv.x))));
        float b01 = fmaf(ea0.x, we0.y, fmaf(ea0.y, we1.y, fmaf(ea0.z, we2.y, fmaf(ea0.w, we3.y, xrv.y))));
        float b10 = fmaf(ea1.x, we0.x, fmaf(ea1.y, we1.x, fmaf(ea1.z, we2.x, fmaf(ea1.w, we3.x, xrv.x))));
        float b11 = fmaf(ea1.x, we0.y, fmaf(ea1.y, we1.y, fmaf(ea1.z, we2.y, fmaf(ea1.w, we3.y, xrv.y))));
        float b20 = fmaf(ea2.x, we0.x, fmaf(ea2.y, we1.x, fmaf(ea2.z, we2.x, fmaf(ea2.w, we3.x, xrv.x))));
        float b21 = fmaf(ea2.x, we0.y, fmaf(ea2.y, we1.y, fmaf(ea2.z, we2.y, fmaf(ea2.w, we3.y, xrv.y))));
        float b30 = fmaf(ea3.x, we0.x, fmaf(ea3.y, we1.x, fmaf(ea3.z, we2.x, fmaf(ea3.w, we3.x, xrv.x))));
        float b31 = fmaf(ea3.x, we0.y, fmaf(ea3.y, we1.y, fmaf(ea3.z, we2.y, fmaf(ea3.w, we3.y, xrv.y))));

        s0 += ea0.x + ea1.x + ea2.x + ea3.x;
        s1 += ea0.y + ea1.y + ea2.y + ea3.y;
        s2 += ea0.z + ea1.z + ea2.z + ea3.z;
        s3 += ea0.w + ea1.w + ea2.w + ea3.w;

        // unpack bf16 pairs
        float x00 = __uint_as_float(xg0 << 16), x01 = __uint_as_float(xg0 & 0xffff0000u);
        float x10 = __uint_as_float(xg1 << 16), x11 = __uint_as_float(xg1 & 0xffff0000u);
        float x20 = __uint_as_float(xg2 << 16), x21 = __uint_as_float(xg2 & 0xffff0000u);
        float x30 = __uint_as_float(xg3 << 16), x31 = __uint_as_float(xg3 & 0xffff0000u);

        // z, leakyrelu(z) = max(z, 0.2z), att partial
        float z;
        z = x00 + b00; float l00 = fmaxf(z, 0.2f * z);
        z = x01 + b01; float l01 = fmaxf(z, 0.2f * z);
        z = x10 + b10; float l10 = fmaxf(z, 0.2f * z);
        z = x11 + b11; float l11 = fmaxf(z, 0.2f * z);
        z = x20 + b20; float l20 = fmaxf(z, 0.2f * z);
        z = x21 + b21; float l21 = fmaxf(z, 0.2f * z);
        z = x30 + b30; float l30 = fmaxf(z, 0.2f * z);
        z = x31 + b31; float l31 = fmaxf(z, 0.2f * z);

        float pt0 = l00 * attv.x + l01 * attv.y;
        float pt1 = l10 * attv.x + l11 * attv.y;
        float pt2 = l20 * attv.x + l21 * attv.y;
        float pt3 = l30 * attv.x + l31 * attv.y;

        // tail mask (uniform): dead slots get -1e30 -> pe = 0
        int rem = p1 - p;
        pt1 = (rem > 1) ? pt1 : -1e30f;
        pt2 = (rem > 2) ? pt2 : -1e30f;
        pt3 = (rem > 3) ? pt3 : -1e30f;

        // per-head logit reduce (pure VALU, 4 independent chains)
        float al0 = hred8(pt0);
        float al1 = hred8(pt1);
        float al2 = hred8(pt2);
        float al3 = hred8(pt3);

        // batched online-softmax update
        float bmax = fmaxf(fmaxf(al0, al1), fmaxf(al2, al3));
        float mnew = fmaxf(m_run, bmax);
        float sc  = __expf(m_run - mnew);
        float pe0 = __expf(al0 - mnew);
        float pe1 = __expf(al1 - mnew);
        float pe2 = __expf(al2 - mnew);
        float pe3 = __expf(al3 - mnew);
        l_run = fmaf(l_run, sc, (pe0 + pe1) + (pe2 + pe3));
        a0 = a0 * sc;
        a0 = fmaf(pe0, x00, a0); a0 = fmaf(pe1, x10, a0);
        a0 = fmaf(pe2, x20, a0); a0 = fmaf(pe3, x30, a0);
        a1 = a1 * sc;
        a1 = fmaf(pe0, x01, a1); a1 = fmaf(pe1, x11, a1);
        a1 = fmaf(pe2, x21, a1); a1 = fmaf(pe3, x31, a1);
        m_run = mnew;
    }

    // self loop last: ea = mean of incoming (pads contributed 0), src = dst
    float inv = 1.0f / (float)(dv > 0 ? dv : 1);
    float x0 = __uint_as_float(xsw << 16);
    float x1 = __uint_as_float(xsw & 0xffff0000u);
    float e0 = (s0 * we0.x + s1 * we1.x + s2 * we2.x + s3 * we3.x) * inv;
    float e1 = (s0 * we0.y + s1 * we1.y + s2 * we2.y + s3 * we3.y) * inv;
    float m0 = x0 + xrv.x + e0; m0 = fmaxf(m0, 0.2f * m0);
    float m1 = x1 + xrv.y + e1; m1 = fmaxf(m1, 0.2f * m1);
    float al = hred8(m0 * attv.x + m1 * attv.y);
    float mnew = fmaxf(m_run, al);
    float sc = __expf(m_run - mnew);
    float pe = __expf(al - mnew);
    l_out = fmaf(l_run, sc, pe);
    r0_out = fmaf(pe, x0, a0 * sc);
    r1_out = fmaf(pe, x1, a1 * sc);
}

// layers 0,1: concat heads, +bias, ELU, LN(128), residual. 4 dst per 256-thread block.
__global__ __launch_bounds__(256) void attn_concat(
    const ushort* __restrict__ xlb, const float* __restrict__ xr,
    const float* __restrict__ xin,
    const int* __restrict__ rowstart, const int* __restrict__ deg,
    const int* __restrict__ src_sorted, const float4* __restrict__ ea_sorted,
    const float* __restrict__ We, const float* __restrict__ att,
    const float* __restrict__ bias, const float* __restrict__ g, const float* __restrict__ be,
    float* __restrict__ out, int n)
{
    int wid = threadIdx.x >> 6;
    int t = threadIdx.x & 63;
    int dstv = blockIdx.x * 4 + wid;
    if (dstv >= n) return;

    float r0, r1, l;
    gat_wave(dstv, t, (const uint*)xlb, xr, rowstart, deg, src_sorted, ea_sorted, We, att, r0, r1, l);

    float2 bv = ((const float2*)bias)[t];
    float linv = 1.0f / l;
    float h0 = r0 * linv + bv.x;
    float h1 = r1 * linv + bv.y;
    h0 = h0 > 0.f ? h0 : (__expf(h0) - 1.0f);
    h1 = h1 > 0.f ? h1 : (__expf(h1) - 1.0f);

    float ss = h0 + h1, qq = h0*h0 + h1*h1;
    #pragma unroll
    for (int o = 1; o < 64; o <<= 1) { ss += __shfl_xor(ss, o); qq += __shfl_xor(qq, o); }
    float mu = ss * (1.0f / ND);
    float var = qq * (1.0f / ND) - mu * mu;
    float rstd = rsqrtf(var + 1e-5f);

    float2 gv = ((const float2*)g)[t];
    float2 bev = ((const float2*)be)[t];
    float2 xiv = ((const float2*)(xin + (size_t)dstv * ND))[t];
    float2 o2;
    o2.x = (h0 - mu) * rstd * gv.x + bev.x + xiv.x;
    o2.y = (h1 - mu) * rstd * gv.y + bev.y + xiv.y;
    ((float2*)(out + (size_t)dstv * ND))[t] = o2;
}

// layer 2: mean over heads, +bias, ELU, LN(16), @Wout[16,128]+bout
__global__ __launch_bounds__(256) void attn_final(
    const ushort* __restrict__ xlb, const float* __restrict__ xr,
    const int* __restrict__ rowstart, const int* __restrict__ deg,
    const int* __restrict__ src_sorted, const float4* __restrict__ ea_sorted,
    const float* __restrict__ We, const float* __restrict__ att,
    const float* __restrict__ b2, const float* __restrict__ g2, const float* __restrict__ be2,
    const float* __restrict__ Wout, const float* __restrict__ bout,
    float* __restrict__ out, int n)
{
    __shared__ float h16s[4][16];
    int wid = threadIdx.x >> 6;
    int t = threadIdx.x & 63;
    int dstv = blockIdx.x * 4 + wid;
    if (dstv >= n) return;

    float r0, r1, l;
    gat_wave(dstv, t, (const uint*)xlb, xr, rowstart, deg, src_sorted, ea_sorted, We, att, r0, r1, l);
    float linv = 1.0f / l;
    r0 *= linv; r1 *= linv;

    // mean over 8 heads: sum over lanes differing in bits 3,4,5
    float v0 = r0, v1 = r1;
    #pragma unroll
    for (int o = 8; o < 64; o <<= 1) { v0 += __shfl_xor(v0, o); v1 += __shfl_xor(v1, o); }
    int cc = t & 7;   // channel pair index: channels 2cc, 2cc+1
    float2 b2v = ((const float2*)b2)[cc];
    v0 = v0 * (1.0f / NH) + b2v.x;
    v1 = v1 * (1.0f / NH) + b2v.y;
    v0 = v0 > 0.f ? v0 : (__expf(v0) - 1.0f);
    v1 = v1 > 0.f ? v1 : (__expf(v1) - 1.0f);

    // LN over 16 (values duplicated across the 8 head-groups)
    float ss = v0 + v1, qq = v0*v0 + v1*v1;
    #pragma unroll
    for (int o = 1; o < 8; o <<= 1) { ss += __shfl_xor(ss, o); qq += __shfl_xor(qq, o); }
    float mu = ss * (1.0f / NC);
    float var = qq * (1.0f / NC) - mu * mu;
    float rstd = rsqrtf(var + 1e-5f);
    float2 g2v = ((const float2*)g2)[cc];
    float2 be2v = ((const float2*)be2)[cc];
    float t0 = (v0 - mu) * rstd * g2v.x + be2v.x;
    float t1 = (v1 - mu) * rstd * g2v.y + be2v.y;

    if (t < 8) { h16s[wid][2*t] = t0; h16s[wid][2*t + 1] = t1; }

    float2 ov = ((const float2*)bout)[t];
    #pragma unroll
    for (int k = 0; k < NC; k++) {
        float hk = h16s[wid][k];
        float2 wv = ((const float2*)Wout)[k * 64 + t];
        ov.x = fmaf(hk, wv.x, ov.x);
        ov.y = fmaf(hk, wv.y, ov.y);
    }
    ((float2*)(out + (size_t)dstv * ND))[t] = ov;
}

// ---------------- launch ----------------

extern "C" void kernel_launch(void* const* d_in, const int* in_sizes, int n_in,
                              void* d_out, int out_size, void* d_ws, size_t ws_size,
                              hipStream_t stream)
{
    const float* x_in = (const float*)d_in[0];
    const int*   ei   = (const int*)d_in[1];
    const float* ea   = (const float*)d_in[2];
    const int N = in_sizes[0] / ND;
    const int E = in_sizes[1] / 2;
    const int* srcs = ei;
    const int* dsts = ei + E;
    const float4* ea4 = (const float4*)ea;

    const float *Wl[3], *bl[3], *Wr[3], *br[3], *We[3], *att[3], *bb[3], *gg[3], *be[3];
    for (int l = 0; l < 3; l++) {
        int b = 3 + 9 * l;
        Wl[l]  = (const float*)d_in[b + 0];
        bl[l]  = (const float*)d_in[b + 1];
        Wr[l]  = (const float*)d_in[b + 2];
        br[l]  = (const float*)d_in[b + 3];
        We[l]  = (const float*)d_in[b + 4];
        att[l] = (const float*)d_in[b + 5];
        bb[l]  = (const float*)d_in[b + 6];
        gg[l]  = (const float*)d_in[b + 7];
        be[l]  = (const float*)d_in[b + 8];
    }
    const float* Wout = (const float*)d_in[30];
    const float* bout = (const float*)d_in[31];

    // padded edge capacity: each of N rows pads to multiple of 4 (+ guard for prefetch)
    const size_t EP = (size_t)E + 3 * (size_t)N + 64;

    char* ws = (char*)d_ws;
    size_t off = 0;
    int* deg        = (int*)(ws + off);      off = alignup(off + (size_t)N * 4);
    int* cursor     = (int*)(ws + off);      off = alignup(off + (size_t)N * 4);
    int* src_sorted = (int*)(ws + off);      off = alignup(off + EP * 4);
    float4* ea_sorted = (float4*)(ws + off); off = alignup(off + EP * 16);
    size_t zero_bytes = off;                 // deg + cursor + src_sorted + ea_sorted
    int* rowstart   = (int*)(ws + off);      off = alignup(off + (size_t)(N + 1) * 4);
    ushort* xlb     = (ushort*)(ws + off);   off = alignup(off + (size_t)N * ND * 2);
    float* xr       = (float*)(ws + off);    off = alignup(off + (size_t)N * ND * 4);
    float* xa       = (float*)(ws + off);    off = alignup(off + (size_t)N * ND * 4);
    float* xb       = (float*)d_out;         // layer-1 output lives in d_out

    hipMemsetAsync(d_ws, 0, zero_bytes, stream);

    int ethreads = 256;
    int eblocks = (E + ethreads - 1) / ethreads;
    hist_kernel<<<eblocks, ethreads, 0, stream>>>(dsts, deg, E);
    scan_kernel<<<1, 1024, 0, stream>>>(deg, rowstart, N);
    scatter_kernel<<<eblocks, ethreads, 0, stream>>>(srcs, dsts, ea4, rowstart, cursor,
                                                     src_sorted, ea_sorted, E);

    int gblocks = (N + 63) / 64;
    int ablocks = (N + 3) / 4;

    // layer 0
    gemm_xw2<<<gblocks, 256, 0, stream>>>(x_in, Wl[0], bl[0], Wr[0], br[0], xlb, xr, N);
    attn_concat<<<ablocks, 256, 0, stream>>>(xlb, xr, x_in, rowstart, deg, src_sorted, ea_sorted,
                                             We[0], att[0], bb[0], gg[0], be[0], xa, N);
    // layer 1
    gemm_xw2<<<gblocks, 256, 0, stream>>>(xa, Wl[1], bl[1], Wr[1], br[1], xlb, xr, N);
    attn_concat<<<ablocks, 256, 0, stream>>>(xlb, xr, xa, rowstart, deg, src_sorted, ea_sorted,
                                             We[1], att[1], bb[1], gg[1], be[1], xb, N);
    // layer 2 + output projection
    gemm_xw2<<<gblocks, 256, 0, stream>>>(xb, Wl[2], bl[2], Wr[2], br[2], xlb, xr, N);
    attn_final<<<ablocks, 256, 0, stream>>>(xlb, xr, rowstart, deg, src_sorted, ea_sorted,
                                            We[2], att[2], bb[2], gg[2], be[2],
                                            Wout, bout, (float*)d_out, N);
}